// Round 1
// baseline (120.563 us; speedup 1.0000x reference)
//
#include <hip/hip_runtime.h>

#define K_NN 16
#define JITTER 1e-4f
#define NPTS 16384
#define M_IND 512

// ---------------- Kernel 1: A = Kzz + JITTER*I  (512x512) ----------------
__global__ void vnngp_kzz_kernel(const float* __restrict__ Z,
                                 const float* __restrict__ lls,
                                 const float* __restrict__ lvar,
                                 float* __restrict__ A) {
    int id = blockIdx.x * blockDim.x + threadIdx.x;
    if (id >= M_IND * M_IND) return;
    int i = id >> 9, j = id & 511;
    float ls = __expf(lls[0]);
    float var = __expf(lvar[0]);
    float inv2 = 0.5f / (ls * ls);
    float d2 = 0.f;
#pragma unroll
    for (int t = 0; t < 8; ++t) {
        float df = Z[i * 8 + t] - Z[j * 8 + t];
        d2 = fmaf(df, df, d2);
    }
    float v = var * __expf(-d2 * inv2);
    if (i == j) v += JITTER;
    A[id] = v;
}

// ---------------- Kernel 2: S = Lu * Lu^T (Lu built on the fly) ----------
// 32x32 output tile per block, 256 threads (16x16), 2x2 per thread.
__global__ void vnngp_lult_kernel(const float* __restrict__ Lu_raw,
                                  float* __restrict__ S) {
    __shared__ float tI[32][33];
    __shared__ float tJ[32][33];
    int tx = threadIdx.x & 15, ty = threadIdx.x >> 4;
    int bi = (blockIdx.x & 15) * 32;
    int bj = (blockIdx.x >> 4) * 32;
    float acc00 = 0.f, acc01 = 0.f, acc10 = 0.f, acc11 = 0.f;
    for (int k0 = 0; k0 < 512; k0 += 32) {
#pragma unroll
        for (int p = 0; p < 4; ++p) {
            int e = threadIdx.x + p * 256;
            int r = e >> 5, cc = e & 31;
            int col = k0 + cc;
            int rowi = bi + r;
            float v = Lu_raw[rowi * 512 + col];
            v = (col < rowi) ? v : ((col == rowi) ? __expf(v) : 0.f);
            tI[r][cc] = v;
            int rowj = bj + r;
            float w = Lu_raw[rowj * 512 + col];
            w = (col < rowj) ? w : ((col == rowj) ? __expf(w) : 0.f);
            tJ[r][cc] = w;
        }
        __syncthreads();
#pragma unroll
        for (int kk = 0; kk < 32; ++kk) {
            float a0 = tI[ty][kk], a1 = tI[ty + 16][kk];
            float b0 = tJ[tx][kk], b1 = tJ[tx + 16][kk];
            acc00 = fmaf(a0, b0, acc00);
            acc01 = fmaf(a0, b1, acc01);
            acc10 = fmaf(a1, b0, acc10);
            acc11 = fmaf(a1, b1, acc11);
        }
        __syncthreads();
    }
    S[(bi + ty) * 512 + (bj + tx)]           = acc00;
    S[(bi + ty) * 512 + (bj + tx + 16)]      = acc01;
    S[(bi + ty + 16) * 512 + (bj + tx)]      = acc10;
    S[(bi + ty + 16) * 512 + (bj + tx + 16)] = acc11;
}

// ---------------- Kernel 3: main — one wave per query point --------------
__launch_bounds__(256)
__global__ void vnngp_main_kernel(const float* __restrict__ X,
                                  const float* __restrict__ Zg,
                                  const float* __restrict__ mu,
                                  const float* __restrict__ lls,
                                  const float* __restrict__ lvar,
                                  const float* __restrict__ A,
                                  const float* __restrict__ S,
                                  float* __restrict__ out) {
    __shared__ float Zs[512][9];  // padded: stride 9 -> conflict-free
    const int tid = threadIdx.x;
    for (int e = tid; e < 512 * 8; e += 256) {
        int z = e >> 3, d = e & 7;
        Zs[z][d] = Zg[e];
    }
    __syncthreads();

    const int lane = tid & 63;
    const int wv = tid >> 6;
    const int n = blockIdx.x * 4 + wv;
    const int jj = lane & 15;

    const float ls = __expf(lls[0]);
    const float var = __expf(lvar[0]);
    const float inv2 = 0.5f / (ls * ls);

    float xv[8];
#pragma unroll
    for (int d = 0; d < 8; ++d) xv[d] = X[n * 8 + d];

    // distances: lane handles z = r*64 + lane, r=0..7
    unsigned long long key[8];
#pragma unroll
    for (int r = 0; r < 8; ++r) {
        int z = r * 64 + lane;
        float d2 = 0.f;
#pragma unroll
        for (int d = 0; d < 8; ++d) {
            float df = xv[d] - Zs[z][d];
            d2 = fmaf(df, df, d2);
        }
        key[r] = (((unsigned long long)__float_as_uint(d2)) << 32) | (unsigned)z;
    }

    // top-16 selection (set only; order irrelevant by permutation invariance)
    unsigned removed = 0;
    int mySel = 0;
    float myKxz = 0.f;
#pragma unroll
    for (int round = 0; round < 16; ++round) {
        unsigned long long m = ~0ull;
#pragma unroll
        for (int r = 0; r < 8; ++r) {
            unsigned long long kk2 = (removed & (1u << r)) ? ~0ull : key[r];
            m = (kk2 < m) ? kk2 : m;
        }
#pragma unroll
        for (int off = 32; off > 0; off >>= 1) {
            unsigned long long o = __shfl_xor(m, off);
            m = (o < m) ? o : m;
        }
        int z = (int)(unsigned)m;
        if ((z & 63) == lane) removed |= 1u << (z >> 6);
        if (lane == round) {
            mySel = z;
            float d2 = __uint_as_float((unsigned)(m >> 32));
            myKxz = var * __expf(-d2 * inv2);
        }
    }

    // gather B column jj: c[i] = A[sel_i, sel_jj] (+ jitter on diag).
    // Only lanes 0..15 load (predicated); lanes >=16 replicate harmlessly.
    const int selJ = __shfl(mySel, jj);
    float c[16];
#pragma unroll
    for (int i = 0; i < 16; ++i) {
        int si = __shfl(mySel, i);
        float v = (lane < 16) ? A[si * 512 + selJ] : 0.f;
        if (i == jj) v += JITTER;
        c[i] = v;
    }

    // Cholesky (column per lane) with fused forward solve L y = kxz.
    float myInvd = 0.f;
    float rbs = myKxz;  // residual owned per lane (lane<16)
#pragma unroll
    for (int k = 0; k < 16; ++k) {
        float dsq = __shfl(c[k], k);
        float dkk = sqrtf(dsq);
        float invd = 1.0f / dkk;
        if (jj == k) myInvd = invd;
        float yk = __shfl(rbs, k) * invd;
        float Ljk = c[k] * invd;  // valid for jj>k (pre-scaled symmetric trick)
        if (jj > k) rbs = fmaf(-Ljk, yk, rbs);
        if (jj == k) rbs = yk;
#pragma unroll
        for (int i = k + 1; i < 16; ++i) {
            float Lik = __shfl(c[i], k) * invd;
            if (jj > k) c[i] = fmaf(-Lik, Ljk, c[i]);
            if (jj == k) c[i] = Lik;
        }
        if (jj == k) c[k] = dkk;
    }

    // backward solve L^T w = y ; w replicated into wreg[] on all lanes
    float r2 = rbs;
    float wreg[16];
#pragma unroll
    for (int k = 15; k >= 0; --k) {
        float invd = __shfl(myInvd, k);
        float wk = __shfl(r2, k) * invd;
        wreg[k] = wk;
        if (jj < k) r2 = fmaf(-c[k], wk, r2);
    }

    // outputs: mean = w.mu_sub ; q1 = w.kxz - eps*|w|^2 ; q2 = w^T S_sub w
    float myMu = (lane < 16) ? mu[mySel] : 0.f;
    float mean = 0.f, wkxz = 0.f, wsq = 0.f;
#pragma unroll
    for (int k = 0; k < 16; ++k) {
        float wk = wreg[k];
        mean = fmaf(wk, __shfl(myMu, k), mean);
        wkxz = fmaf(wk, __shfl(myKxz, k), wkxz);
        wsq = fmaf(wk, wk, wsq);
    }
    float t = 0.f;
#pragma unroll
    for (int k = 0; k < 16; ++k) {
        int si = __shfl(mySel, k);
        float sv = (lane < 16) ? S[si * 512 + selJ] : 0.f;
        t = fmaf(wreg[k], sv, t);
    }
    float q2 = 0.f;
#pragma unroll
    for (int k = 0; k < 16; ++k) q2 = fmaf(wreg[k], __shfl(t, k), q2);

    if (lane == 0) {
        float cov = var - (wkxz - JITTER * wsq) + q2;
        float sd = sqrtf(fmaxf(cov, 0.05f));
        out[n] = mean;
        out[NPTS + n] = sd;
    }
}

extern "C" void kernel_launch(void* const* d_in, const int* in_sizes, int n_in,
                              void* d_out, int out_size, void* d_ws, size_t ws_size,
                              hipStream_t stream) {
    const float* X = (const float*)d_in[0];
    const float* Z = (const float*)d_in[1];
    const float* Lu_raw = (const float*)d_in[2];
    const float* mu = (const float*)d_in[3];
    const float* lls = (const float*)d_in[4];
    const float* lvar = (const float*)d_in[5];
    float* out = (float*)d_out;

    float* A = (float*)d_ws;             // 512*512 floats = 1 MB
    float* S = A + M_IND * M_IND;        // 512*512 floats = 1 MB

    vnngp_kzz_kernel<<<(M_IND * M_IND + 255) / 256, 256, 0, stream>>>(Z, lls, lvar, A);
    vnngp_lult_kernel<<<256, 256, 0, stream>>>(Lu_raw, S);
    vnngp_main_kernel<<<NPTS / 4, 256, 0, stream>>>(X, Z, mu, lls, lvar, A, S, out);
}

// Round 2
// 86.086 us; speedup vs baseline: 1.4005x; 1.4005x over previous
//
#include <hip/hip_runtime.h>

#define K_NN 16
#define JITTER 1e-4f
#define NPTS 16384
#define M_IND 512

// ---------------- helpers ----------------
__device__ __forceinline__ float rlf(float v, int l) {
    return __int_as_float(__builtin_amdgcn_readlane(__float_as_int(v), l));
}

#define DPP_MIN_STEP(v, ctrl)                                                           \
    {                                                                                   \
        unsigned _t = (unsigned)__builtin_amdgcn_update_dpp((int)(v), (int)(v), (ctrl), \
                                                            0xF, 0xF, false);           \
        (v) = (_t < (v)) ? _t : (v);                                                    \
    }

#define CE(a, b)                         \
    {                                    \
        unsigned _lo = (s[a] < s[b]) ? s[a] : s[b]; \
        unsigned _hi = (s[a] < s[b]) ? s[b] : s[a]; \
        s[a] = _lo; s[b] = _hi;          \
    }

// ---------------- Kernel 1: A = Kzz + JITTER*I  (512x512) ----------------
__global__ void vnngp_kzz_kernel(const float* __restrict__ Z,
                                 const float* __restrict__ lls,
                                 const float* __restrict__ lvar,
                                 float* __restrict__ A) {
    int id = blockIdx.x * blockDim.x + threadIdx.x;
    if (id >= M_IND * M_IND) return;
    int i = id >> 9, j = id & 511;
    float ls = __expf(lls[0]);
    float var = __expf(lvar[0]);
    float inv2 = 0.5f / (ls * ls);
    float d2 = 0.f;
#pragma unroll
    for (int t = 0; t < 8; ++t) {
        float df = Z[i * 8 + t] - Z[j * 8 + t];
        d2 = fmaf(df, df, d2);
    }
    float v = var * __expf(-d2 * inv2);
    if (i == j) v += JITTER;
    A[id] = v;
}

// ---------------- Kernel 2: S = Lu * Lu^T (Lu built on the fly) ----------
__global__ void vnngp_lult_kernel(const float* __restrict__ Lu_raw,
                                  float* __restrict__ S) {
    __shared__ float tI[32][33];
    __shared__ float tJ[32][33];
    int tx = threadIdx.x & 15, ty = threadIdx.x >> 4;
    int bi = (blockIdx.x & 15) * 32;
    int bj = (blockIdx.x >> 4) * 32;
    float acc00 = 0.f, acc01 = 0.f, acc10 = 0.f, acc11 = 0.f;
    for (int k0 = 0; k0 < 512; k0 += 32) {
#pragma unroll
        for (int p = 0; p < 4; ++p) {
            int e = threadIdx.x + p * 256;
            int r = e >> 5, cc = e & 31;
            int col = k0 + cc;
            int rowi = bi + r;
            float v = Lu_raw[rowi * 512 + col];
            v = (col < rowi) ? v : ((col == rowi) ? __expf(v) : 0.f);
            tI[r][cc] = v;
            int rowj = bj + r;
            float w = Lu_raw[rowj * 512 + col];
            w = (col < rowj) ? w : ((col == rowj) ? __expf(w) : 0.f);
            tJ[r][cc] = w;
        }
        __syncthreads();
#pragma unroll
        for (int kk = 0; kk < 32; ++kk) {
            float a0 = tI[ty][kk], a1 = tI[ty + 16][kk];
            float b0 = tJ[tx][kk], b1 = tJ[tx + 16][kk];
            acc00 = fmaf(a0, b0, acc00);
            acc01 = fmaf(a0, b1, acc01);
            acc10 = fmaf(a1, b0, acc10);
            acc11 = fmaf(a1, b1, acc11);
        }
        __syncthreads();
    }
    S[(bi + ty) * 512 + (bj + tx)]           = acc00;
    S[(bi + ty) * 512 + (bj + tx + 16)]      = acc01;
    S[(bi + ty + 16) * 512 + (bj + tx)]      = acc10;
    S[(bi + ty + 16) * 512 + (bj + tx + 16)] = acc11;
}

// ---------------- Kernel 3: main — one wave per query point --------------
__launch_bounds__(256)
__global__ void vnngp_main_kernel(const float* __restrict__ X,
                                  const float* __restrict__ Zg,
                                  const float* __restrict__ mu,
                                  const float* __restrict__ lls,
                                  const float* __restrict__ lvar,
                                  const float* __restrict__ A,
                                  const float* __restrict__ S,
                                  float* __restrict__ out) {
    __shared__ float Zs[512][9];  // stride 9 words: lane*9 mod 32 -> 2-way (free)
    const int tid = threadIdx.x;
    for (int e = tid; e < 512 * 8; e += 256) {
        Zs[e >> 3][e & 7] = Zg[e];
    }
    __syncthreads();

    const int lane = tid & 63;
    const int wv = tid >> 6;
    const int n = blockIdx.x * 4 + wv;
    const int jj = lane & 15;

    const float ls = __expf(lls[0]);
    const float var = __expf(lvar[0]);
    const float inv2 = 0.5f / (ls * ls);

    float xv[8];
#pragma unroll
    for (int d = 0; d < 8; ++d) xv[d] = X[n * 8 + d];

    // 32-bit packed keys: high 23 bits of d2, low 9 bits index. Lane owns z = r*64+lane.
    unsigned s[8];
#pragma unroll
    for (int r = 0; r < 8; ++r) {
        int z = r * 64 + lane;
        float d2 = 0.f;
#pragma unroll
        for (int d = 0; d < 8; ++d) {
            float df = xv[d] - Zs[z][d];
            d2 = fmaf(df, df, d2);
        }
        s[r] = (__float_as_uint(d2) & 0xFFFFFE00u) | (unsigned)z;
    }

    // per-lane ascending sort (Batcher 8-network, 19 CE)
    CE(0, 1) CE(2, 3) CE(4, 5) CE(6, 7)
    CE(0, 2) CE(1, 3) CE(4, 6) CE(5, 7)
    CE(1, 2) CE(5, 6)
    CE(0, 4) CE(1, 5) CE(2, 6) CE(3, 7)
    CE(2, 4) CE(3, 5)
    CE(1, 2) CE(3, 4) CE(5, 6)

    // 16 rounds of wave-min over per-lane heads; winner shifts its list.
    int mySel = 0;
#pragma unroll
    for (int round = 0; round < 16; ++round) {
        unsigned mv = s[0];
        DPP_MIN_STEP(mv, 0x111)  // row_shr:1
        DPP_MIN_STEP(mv, 0x112)  // row_shr:2
        DPP_MIN_STEP(mv, 0x114)  // row_shr:4
        DPP_MIN_STEP(mv, 0x118)  // row_shr:8
        DPP_MIN_STEP(mv, 0x142)  // row_bcast15
        DPP_MIN_STEP(mv, 0x143)  // row_bcast31
        unsigned m = (unsigned)__builtin_amdgcn_readlane((int)mv, 63);
        bool amW = (s[0] == m);  // unique: index embedded in key
#pragma unroll
        for (int i = 0; i < 7; ++i) s[i] = amW ? s[i + 1] : s[i];
        s[7] = amW ? 0xFFFFFFFFu : s[7];
        if (lane == round) mySel = (int)(m & 511u);
    }

    // exact Kxz for the selected point (removes key quantization error)
    float d2e = 0.f;
#pragma unroll
    for (int d = 0; d < 8; ++d) {
        float df = xv[d] - Zs[mySel][d];
        d2e = fmaf(df, df, d2e);
    }
    const float myKxz = var * __expf(-d2e * inv2);

    // gather B column jj: c[i] = A[sel_i, sel_jj] (+ jitter on diag)
    const int selJ = __shfl(mySel, jj);
    float c[16];
#pragma unroll
    for (int i = 0; i < 16; ++i) {
        int si = __builtin_amdgcn_readlane(mySel, i);
        float v = A[si * 512 + selJ];
        v += (jj == i) ? JITTER : 0.f;
        c[i] = v;
    }

    // Cholesky (column per lane, lanes 0-15 meaningful) + fused forward solve
    float myInvd = 0.f;
    float rbs = myKxz;
#pragma unroll
    for (int k = 0; k < 16; ++k) {
        float dsq = rlf(c[k], k);
        float invd = rsqrtf(dsq);
        bool eq = (jj == k), gt = (jj > k);
        if (eq) myInvd = invd;
        float yk = rlf(rbs, k) * invd;
        float Ljk = c[k] * invd;  // lanes jj>k: L[jj][k] via symmetry
        float nr = fmaf(-Ljk, yk, rbs);
        rbs = eq ? yk : (gt ? nr : rbs);
#pragma unroll
        for (int i = k + 1; i < 16; ++i) {
            float Lik = rlf(c[i], k) * invd;
            float upd = fmaf(-Lik, Ljk, c[i]);
            c[i] = eq ? Lik : (gt ? upd : c[i]);
        }
    }

    // backward solve L^T w = y
    float r2 = rbs;
    float wreg[16];
#pragma unroll
    for (int k = 15; k >= 0; --k) {
        float wk = rlf(r2, k) * rlf(myInvd, k);
        wreg[k] = wk;
        if (jj < k) r2 = fmaf(-c[k], wk, r2);
    }

    // outputs: mean = w.mu ; q1 = w.kxz - eps|w|^2 ; q2 = w^T S_sub w
    float myMu = mu[mySel];
    float mean = 0.f, wkxz = 0.f, wsq = 0.f;
#pragma unroll
    for (int k = 0; k < 16; ++k) {
        float wk = wreg[k];
        mean = fmaf(wk, rlf(myMu, k), mean);
        wkxz = fmaf(wk, rlf(myKxz, k), wkxz);
        wsq = fmaf(wk, wk, wsq);
    }
    float t = 0.f;
#pragma unroll
    for (int k = 0; k < 16; ++k) {
        int si = __builtin_amdgcn_readlane(mySel, k);
        t = fmaf(wreg[k], S[si * 512 + selJ], t);
    }
    float q2 = 0.f;
#pragma unroll
    for (int k = 0; k < 16; ++k) q2 = fmaf(wreg[k], rlf(t, k), q2);

    if (lane == 0) {
        float cov = var - (wkxz - JITTER * wsq) + q2;
        float sd = sqrtf(fmaxf(cov, 0.05f));
        out[n] = mean;
        out[NPTS + n] = sd;
    }
}

extern "C" void kernel_launch(void* const* d_in, const int* in_sizes, int n_in,
                              void* d_out, int out_size, void* d_ws, size_t ws_size,
                              hipStream_t stream) {
    const float* X = (const float*)d_in[0];
    const float* Z = (const float*)d_in[1];
    const float* Lu_raw = (const float*)d_in[2];
    const float* mu = (const float*)d_in[3];
    const float* lls = (const float*)d_in[4];
    const float* lvar = (const float*)d_in[5];
    float* out = (float*)d_out;

    float* A = (float*)d_ws;
    float* S = A + M_IND * M_IND;

    vnngp_kzz_kernel<<<(M_IND * M_IND + 255) / 256, 256, 0, stream>>>(Z, lls, lvar, A);
    vnngp_lult_kernel<<<256, 256, 0, stream>>>(Lu_raw, S);
    vnngp_main_kernel<<<NPTS / 4, 256, 0, stream>>>(X, Z, mu, lls, lvar, A, S, out);
}

// Round 3
// 57.821 us; speedup vs baseline: 2.0851x; 1.4888x over previous
//
#include <hip/hip_runtime.h>

#define K_NN 16
#define JITTER 1e-4f
#define NPTS 16384
#define M_IND 512

__device__ __forceinline__ unsigned umin_(unsigned a, unsigned b) { return a < b ? a : b; }
__device__ __forceinline__ unsigned umax_(unsigned a, unsigned b) { return a > b ? a : b; }

// ds_swizzle offset must be a literal -> macro-expand all uses.
#define BC16I(x, K)  __builtin_amdgcn_ds_swizzle((x), (((K) << 5) | 0x10))   // bcast lane K of each 16-group
#define BC16F(x, K)  __int_as_float(BC16I(__float_as_int(x), K))
#define XOR16I(x, X) __builtin_amdgcn_ds_swizzle((x), (((X) << 10) | 0x1F))  // xor butterfly within 16
#define XOR16F(x, X) __int_as_float(XOR16I(__float_as_int(x), X))

#define BMIN16(v) { unsigned _t; \
  _t = (unsigned)XOR16I((int)(v), 1); (v) = umin_((v), _t); \
  _t = (unsigned)XOR16I((int)(v), 2); (v) = umin_((v), _t); \
  _t = (unsigned)XOR16I((int)(v), 4); (v) = umin_((v), _t); \
  _t = (unsigned)XOR16I((int)(v), 8); (v) = umin_((v), _t); }

#define RADD16(v) { float _t; \
  _t = XOR16F((v), 1); (v) += _t; \
  _t = XOR16F((v), 2); (v) += _t; \
  _t = XOR16F((v), 4); (v) += _t; \
  _t = XOR16F((v), 8); (v) += _t; }

#define CEx(A_, a, b) { unsigned _l = umin_(A_[a], A_[b]); unsigned _h = umax_(A_[a], A_[b]); A_[a] = _l; A_[b] = _h; }

#define SORT8(A_, o) \
  CEx(A_, o+0,o+1) CEx(A_, o+2,o+3) CEx(A_, o+4,o+5) CEx(A_, o+6,o+7) \
  CEx(A_, o+0,o+2) CEx(A_, o+1,o+3) CEx(A_, o+4,o+6) CEx(A_, o+5,o+7) \
  CEx(A_, o+1,o+2) CEx(A_, o+5,o+6) \
  CEx(A_, o+0,o+4) CEx(A_, o+1,o+5) CEx(A_, o+2,o+6) CEx(A_, o+3,o+7) \
  CEx(A_, o+2,o+4) CEx(A_, o+3,o+5) \
  CEx(A_, o+1,o+2) CEx(A_, o+3,o+4) CEx(A_, o+5,o+6)

// sort8(lo) + sort8(hi) + bitonic merge (reverse-pair + strides 4,2,1)
#define SORT16(A_) \
  SORT8(A_, 0) SORT8(A_, 8) \
  CEx(A_,0,15) CEx(A_,1,14) CEx(A_,2,13) CEx(A_,3,12) CEx(A_,4,11) CEx(A_,5,10) CEx(A_,6,9) CEx(A_,7,8) \
  CEx(A_,0,4) CEx(A_,1,5) CEx(A_,2,6) CEx(A_,3,7) CEx(A_,8,12) CEx(A_,9,13) CEx(A_,10,14) CEx(A_,11,15) \
  CEx(A_,0,2) CEx(A_,1,3) CEx(A_,4,6) CEx(A_,5,7) CEx(A_,8,10) CEx(A_,9,11) CEx(A_,12,14) CEx(A_,13,15) \
  CEx(A_,0,1) CEx(A_,2,3) CEx(A_,4,5) CEx(A_,6,7) CEx(A_,8,9) CEx(A_,10,11) CEx(A_,12,13) CEx(A_,14,15)

// ---------------- Prep (fused): A = Kzz + eps*I ; S = Lu Lu^T ------------
__global__ void vnngp_prep_kernel(const float* __restrict__ Z,
                                  const float* __restrict__ lls,
                                  const float* __restrict__ lvar,
                                  const float* __restrict__ Lu_raw,
                                  float* __restrict__ A,
                                  float* __restrict__ S) {
    __shared__ float tI[32][33];
    __shared__ float tJ[32][33];
    if (blockIdx.x < 1024) {
        int id = blockIdx.x * 256 + threadIdx.x;
        int i = id >> 9, j = id & 511;
        float ls = __expf(lls[0]);
        float var = __expf(lvar[0]);
        float inv2 = 0.5f / (ls * ls);
        float d2 = 0.f;
#pragma unroll
        for (int t = 0; t < 8; ++t) {
            float df = Z[i * 8 + t] - Z[j * 8 + t];
            d2 = fmaf(df, df, d2);
        }
        float v = var * __expf(-d2 * inv2);
        if (i == j) v += JITTER;
        A[id] = v;
        return;
    }
    int bidx = blockIdx.x - 1024;
    int tx = threadIdx.x & 15, ty = threadIdx.x >> 4;
    int bi = (bidx & 15) * 32;
    int bj = (bidx >> 4) * 32;
    float acc00 = 0.f, acc01 = 0.f, acc10 = 0.f, acc11 = 0.f;
    for (int k0 = 0; k0 < 512; k0 += 32) {
#pragma unroll
        for (int p = 0; p < 4; ++p) {
            int e = threadIdx.x + p * 256;
            int r = e >> 5, cc = e & 31;
            int col = k0 + cc;
            int rowi = bi + r;
            float v = Lu_raw[rowi * 512 + col];
            v = (col < rowi) ? v : ((col == rowi) ? __expf(v) : 0.f);
            tI[r][cc] = v;
            int rowj = bj + r;
            float w = Lu_raw[rowj * 512 + col];
            w = (col < rowj) ? w : ((col == rowj) ? __expf(w) : 0.f);
            tJ[r][cc] = w;
        }
        __syncthreads();
#pragma unroll
        for (int kk = 0; kk < 32; ++kk) {
            float a0 = tI[ty][kk], a1 = tI[ty + 16][kk];
            float b0 = tJ[tx][kk], b1 = tJ[tx + 16][kk];
            acc00 = fmaf(a0, b0, acc00);
            acc01 = fmaf(a0, b1, acc01);
            acc10 = fmaf(a1, b0, acc10);
            acc11 = fmaf(a1, b1, acc11);
        }
        __syncthreads();
    }
    S[(bi + ty) * 512 + (bj + tx)]           = acc00;
    S[(bi + ty) * 512 + (bj + tx + 16)]      = acc01;
    S[(bi + ty + 16) * 512 + (bj + tx)]      = acc10;
    S[(bi + ty + 16) * 512 + (bj + tx + 16)] = acc11;
}

// ---------------- Main: 4 points per wave (16-lane groups) ----------------
#define CHOLK(K) { \
    float dsq = BC16F(c[K], K); \
    float invd = rsqrtf(dsq); \
    bool eq = (q == (K)); bool gt = (q > (K)); \
    if (eq) myInvd = invd; \
    float yk = BC16F(rbs, K) * invd; \
    float Ljk = c[K] * invd; \
    float nr = fmaf(-Ljk, yk, rbs); \
    rbs = eq ? yk : (gt ? nr : rbs); \
    _Pragma("unroll") \
    for (int i = (K) + 1; i < 16; ++i) { \
        float Lik = BC16F(c[i], K) * invd; \
        float upd = fmaf(-Lik, Ljk, c[i]); \
        c[i] = eq ? Lik : (gt ? upd : c[i]); \
    } }

#define AGATH(I) { \
    int si = BC16I(mySel, I); \
    float v = Ap[si * 512 + mySel]; \
    if (q == (I)) v += JITTER; \
    c[I] = v; }

#define BWDK(K) { \
    float wk = BC16F(r2, K) * BC16F(myInvd, K); \
    if (q < (K)) r2 = fmaf(-c[K], wk, r2); \
    if (q == (K)) myW = wk; \
    int siK = BC16I(mySel, K); \
    t = fmaf(wk, Sp[siK * 512 + mySel], t); }

__launch_bounds__(256, 4)
__global__ void vnngp_main_kernel(const float* __restrict__ X,
                                  const float* __restrict__ Zg,
                                  const float* __restrict__ mu,
                                  const float* __restrict__ lls,
                                  const float* __restrict__ lvar,
                                  const float* __restrict__ Ap,
                                  const float* __restrict__ Sp,
                                  float* __restrict__ out) {
    __shared__ float Zs[512 * 12];  // row stride 12 words (48B, b128-aligned)
    const int tid = threadIdx.x;
    for (int e = tid; e < 1024; e += 256) {
        float4 v = ((const float4*)Zg)[e];
        *(float4*)&Zs[(e >> 1) * 12 + (e & 1) * 4] = v;
    }
    __syncthreads();

    const int q = tid & 15;          // column / lane-in-group
    const int n = blockIdx.x * 16 + (tid >> 4);

    const float ls = __expf(lls[0]);
    const float var = __expf(lvar[0]);
    const float inv2 = 0.5f / (ls * ls);

    const float4 x0 = ((const float4*)X)[n * 2];
    const float4 x1 = ((const float4*)X)[n * 2 + 1];
    const float xv[8] = {x0.x, x0.y, x0.z, x0.w, x1.x, x1.y, x1.z, x1.w};

    // distances for z = slot*16 + q, slot 0..31; fixed-point keys (quant 2^-15)
    unsigned sA[16], sB[16];
#pragma unroll
    for (int slot = 0; slot < 32; ++slot) {
        int idx = slot * 192 + q * 12;
        float d2 = 0.f;
#pragma unroll
        for (int d = 0; d < 8; ++d) {
            float df = xv[d] - Zs[idx + d];
            d2 = fmaf(df, df, d2);
        }
        unsigned ki = (unsigned)(d2 * 32768.0f);
        ki = umin_(ki, 0x7FFFFFu);
        unsigned key = (ki << 9) | (unsigned)(slot * 16 + q);
        if (slot < 16) sA[slot] = key; else sB[slot - 16] = key;
    }
    SORT16(sA)
    SORT16(sB)

    // 16 tournament rounds over dual sorted heads (per 16-lane group)
    int mySel = 0;
#pragma unroll
    for (int r = 0; r < 16; ++r) {
        unsigned hA = sA[0], hB = sB[0];
        unsigned mv = umin_(hA, hB);
        BMIN16(mv)
        bool winA = (hA == mv), winB = (hB == mv);
#pragma unroll
        for (int i = 0; i < 15; ++i) sA[i] = winA ? sA[i + 1] : sA[i];
        sA[15] = winA ? 0xFFFFFFFFu : sA[15];
#pragma unroll
        for (int i = 0; i < 15; ++i) sB[i] = winB ? sB[i + 1] : sB[i];
        sB[15] = winB ? 0xFFFFFFFFu : sB[15];
        if (q == r) mySel = (int)(mv & 511u);
    }

    // exact Kxz for own selected index
    float d2e = 0.f;
    {
        int idx = mySel * 12;
#pragma unroll
        for (int d = 0; d < 8; ++d) {
            float df = xv[d] - Zs[idx + d];
            d2e = fmaf(df, df, d2e);
        }
    }
    const float myKxz = var * __expf(-d2e * inv2);

    // gather B column q: c[i] = A[sel_i, sel_q] (+ jitter on diag)
    float c[16];
    AGATH(0) AGATH(1) AGATH(2) AGATH(3) AGATH(4) AGATH(5) AGATH(6) AGATH(7)
    AGATH(8) AGATH(9) AGATH(10) AGATH(11) AGATH(12) AGATH(13) AGATH(14) AGATH(15)

    // Cholesky (column per lane) with fused forward solve L y = kxz
    float myInvd = 0.f;
    float rbs = myKxz;
    CHOLK(0) CHOLK(1) CHOLK(2) CHOLK(3) CHOLK(4) CHOLK(5) CHOLK(6) CHOLK(7)
    CHOLK(8) CHOLK(9) CHOLK(10) CHOLK(11) CHOLK(12) CHOLK(13) CHOLK(14) CHOLK(15)

    // backward solve L^T w = y, fused with t_q = sum_k w_k S[sel_k, sel_q]
    float r2 = rbs;
    float myW = 0.f, t = 0.f;
    BWDK(15) BWDK(14) BWDK(13) BWDK(12) BWDK(11) BWDK(10) BWDK(9) BWDK(8)
    BWDK(7) BWDK(6) BWDK(5) BWDK(4) BWDK(3) BWDK(2) BWDK(1) BWDK(0)

    // epilogue: 4 group reductions over 16 lanes
    float myMu = mu[mySel];
    float pm = myW * myMu;
    float pk = myW * myKxz;
    float pw = myW * myW;
    float pq = myW * t;
    RADD16(pm) RADD16(pk) RADD16(pw) RADD16(pq)

    if (q == 0) {
        float cov = var - (pk - JITTER * pw) + pq;
        out[n] = pm;
        out[NPTS + n] = sqrtf(fmaxf(cov, 0.05f));
    }
}

extern "C" void kernel_launch(void* const* d_in, const int* in_sizes, int n_in,
                              void* d_out, int out_size, void* d_ws, size_t ws_size,
                              hipStream_t stream) {
    const float* X = (const float*)d_in[0];
    const float* Z = (const float*)d_in[1];
    const float* Lu_raw = (const float*)d_in[2];
    const float* mu = (const float*)d_in[3];
    const float* lls = (const float*)d_in[4];
    const float* lvar = (const float*)d_in[5];
    float* out = (float*)d_out;

    float* A = (float*)d_ws;
    float* S = A + M_IND * M_IND;

    vnngp_prep_kernel<<<1280, 256, 0, stream>>>(Z, lls, lvar, Lu_raw, A, S);
    vnngp_main_kernel<<<NPTS / 16, 256, 0, stream>>>(X, Z, mu, lls, lvar, A, S, out);
}